// Round 5
// baseline (33.015 us; speedup 1.0000x reference)
//
#include <hip/hip_runtime.h>

// out[b, e] = sum_d x[b, d] * T[g[b] % G, d, e]
// B=128, D=1024, G=40, f32.
//
// Fused single kernel. Block = (group gi, pass p, 64-column stripe).
// Every active block does exactly ONE pass over its 256 KB T stripe
// (uniform work -> no multi-pass tail); pass-blocks beyond the group's
// sample count exit before touching T. Threads 256 = 16 d-slices x 16
// e-threads; in-block LDS reduce across d-slices writes out directly.
// Compulsory traffic ~= one pass over the used ~155 MB of the table.

#define B_DIM   128
#define D_DIM   1024
#define G_DIM   40
#define SMAX    8      // samples per pass
#define PMAX    3      // max passes (covers group size up to 24; last pass loops)
#define ECH     16     // column stripes
#define ECOLS   64     // columns per block
#define DSL     16     // d-slices per block
#define THREADS 256
// xs row: 256 float4 + 1 pad float4 per 16 -> 272 float4 (bank-spread for
// the 4-distinct-address broadcast reads across d-slices)
#define XROW    272

__global__ __launch_bounds__(THREADS) void leqfc_fused(
    const float* __restrict__ x,
    const int* __restrict__ g,
    const float* __restrict__ T,
    float* __restrict__ out)
{
    const int gi  = blockIdx.x % G_DIM;          // group 0..39
    const int p   = blockIdx.x / G_DIM;          // pass 0..PMAX-1
    const int e0  = blockIdx.y * ECOLS;          // column stripe base
    const int tid = threadIdx.x;
    const int sl  = tid >> 4;                    // d-slice 0..15 (rows sl*64..+63)
    const int eth = tid & 15;                    // cols e0 + eth*4 .. +3

    __shared__ float smem[SMAX * XROW * 4];      // xs (swizzled) / red buffer
    __shared__ int   mem[B_DIM];
    __shared__ int   cnt;

    if (tid == 0) cnt = 0;
    __syncthreads();
    if (tid < B_DIM) {
        if ((g[tid] % G_DIM) == gi)
            mem[atomicAdd(&cnt, 1)] = tid;       // slot order races; per-sample
    }                                            // numerics are slot-invariant
    __syncthreads();
    const int m = cnt;
    if (p * SMAX >= m) return;                   // uniform early exit, no T touched

    const float4* __restrict__ x4 = reinterpret_cast<const float4*>(x);
    const float4* __restrict__ Tp = reinterpret_cast<const float4*>(
        T + (size_t)gi * D_DIM * D_DIM + (size_t)(sl * 64) * D_DIM + e0) + eth;
    float4* smem4 = reinterpret_cast<float4*>(smem);

    for (int s0 = p * SMAX; s0 < m; s0 += SMAX) {
        const int mc = min(SMAX, m - s0);

        __syncthreads();   // previous pass done with smem
        // stage xs: 2048 logical float4 (8 samples x 256), swizzled layout
        #pragma unroll
        for (int k = 0; k < 8; ++k) {
            const int fq = tid + k * THREADS;    // 0..2047
            const int j  = fq >> 8;
            const int dq = fq & 255;
            smem4[j * XROW + dq + (dq >> 4)] =
                (j < mc) ? x4[(size_t)mem[s0 + j] * (D_DIM / 4) + dq]
                         : make_float4(0.f, 0.f, 0.f, 0.f);
        }
        __syncthreads();

        float4 acc[SMAX];
        #pragma unroll
        for (int j = 0; j < SMAX; ++j) acc[j] = make_float4(0.f, 0.f, 0.f, 0.f);

        #pragma unroll 4
        for (int k = 0; k < 16; ++k) {
            const float4 t0 = Tp[(size_t)(4 * k + 0) * (D_DIM / 4)];
            const float4 t1 = Tp[(size_t)(4 * k + 1) * (D_DIM / 4)];
            const float4 t2 = Tp[(size_t)(4 * k + 2) * (D_DIM / 4)];
            const float4 t3 = Tp[(size_t)(4 * k + 3) * (D_DIM / 4)];
            #pragma unroll
            for (int j = 0; j < SMAX; ++j) {
                if (j < mc) {                    // wave-uniform guard
                    // xs[j][sl*16+k] at swizzled offset sl*17 + k
                    const float4 xv = smem4[j * XROW + sl * 17 + k];
                    acc[j].x = fmaf(xv.x, t0.x, fmaf(xv.y, t1.x, fmaf(xv.z, t2.x, fmaf(xv.w, t3.x, acc[j].x))));
                    acc[j].y = fmaf(xv.x, t0.y, fmaf(xv.y, t1.y, fmaf(xv.z, t2.y, fmaf(xv.w, t3.y, acc[j].y))));
                    acc[j].z = fmaf(xv.x, t0.z, fmaf(xv.y, t1.z, fmaf(xv.z, t2.z, fmaf(xv.w, t3.z, acc[j].z))));
                    acc[j].w = fmaf(xv.x, t0.w, fmaf(xv.y, t1.w, fmaf(xv.z, t2.w, fmaf(xv.w, t3.w, acc[j].w))));
                }
            }
        }

        __syncthreads();   // xs reads complete; smem becomes red[8][16][64]
        #pragma unroll
        for (int j = 0; j < SMAX; ++j)
            if (j < mc)
                smem4[(j * DSL + sl) * (ECOLS / 4) + eth] = acc[j];
        __syncthreads();

        // fold 16 d-slices: up to 512 outputs, 2 per thread
        #pragma unroll
        for (int o2 = 0; o2 < 2; ++o2) {
            const int o = tid + o2 * THREADS;    // 0..511
            const int j = o >> 6;
            const int c = o & 63;
            if (j < mc) {
                float s = 0.f;
                #pragma unroll
                for (int ss = 0; ss < DSL; ++ss)
                    s += smem[(j * DSL + ss) * ECOLS + c];
                out[(size_t)mem[s0 + j] * D_DIM + e0 + c] = s;
            }
        }

        if (p != PMAX - 1) break;   // only the last pass-block loops (safety net)
    }
}

extern "C" void kernel_launch(void* const* d_in, const int* in_sizes, int n_in,
                              void* d_out, int out_size, void* d_ws, size_t ws_size,
                              hipStream_t stream)
{
    const float* x = (const float*)d_in[0];
    const int*   g = (const int*)d_in[1];
    const float* T = (const float*)d_in[2];
    float* out = (float*)d_out;

    dim3 grid(G_DIM * PMAX, ECH);   // 120 x 16 = 1920 blocks (~1/3 active)
    leqfc_fused<<<grid, THREADS, 0, stream>>>(x, g, T, out);
}

// Round 7
// 30.498 us; speedup vs baseline: 1.0825x; 1.0825x over previous
//
#include <hip/hip_runtime.h>

// out[b, e] = sum_d x[b, d] * T[g[b] % G, d, e]
// B=128, D=1024, G=40, f32.
//
// R4 structure (best measured: 31.2 us) + nontemporal T loads.
// Block = (group gi, 64-column stripe). Threads 256 = 16 d-slices x 16
// e-threads; each thread owns 4 cols (float4) and 64 rows; in-block LDS
// reduce across d-slices writes out directly. T is a single-use stream
// (each element read exactly once per launch) -> nt loads bypass L2/L3 fill.

#define B_DIM   128
#define D_DIM   1024
#define G_DIM   40
#define SMAX    8      // samples per pass (loop handles rare >8 groups)
#define ECH     16     // column stripes
#define ECOLS   64     // columns per block
#define DSL     16     // d-slices per block
#define THREADS 256

// native clang vector type: __builtin_nontemporal_load rejects HIP_vector_type
typedef float f4 __attribute__((ext_vector_type(4)));

__global__ __launch_bounds__(THREADS) void leqfc_fused(
    const float* __restrict__ x,
    const int* __restrict__ g,
    const float* __restrict__ T,
    float* __restrict__ out)
{
    const int gi  = blockIdx.x;          // 0..39
    const int e0  = blockIdx.y * ECOLS;  // column stripe base
    const int tid = threadIdx.x;
    const int sl  = tid >> 4;            // d-slice 0..15 (rows sl*64 .. +63)
    const int eth = tid & 15;            // e-thread: cols e0 + eth*4 .. +3

    // xs[8][1024] (32 KB) during the d-loop; red[8][16][64] (32 KB) after.
    __shared__ float smem[SMAX * D_DIM];
    __shared__ int   mem[B_DIM];
    __shared__ int   cnt;

    if (tid == 0) cnt = 0;
    __syncthreads();
    if (tid < B_DIM) {
        if ((g[tid] % G_DIM) == gi)
            mem[atomicAdd(&cnt, 1)] = tid;   // slot order races; per-sample
    }                                        // numerics are slot-invariant
    __syncthreads();
    const int m = cnt;

    const f4* __restrict__ x4 = reinterpret_cast<const f4*>(x);
    const f4* __restrict__ Tp = reinterpret_cast<const f4*>(
        T + (size_t)gi * D_DIM * D_DIM + (size_t)(sl * 64) * D_DIM + e0) + eth;
    f4* smem4 = reinterpret_cast<f4*>(smem);

    for (int s0 = 0; s0 < m; s0 += SMAX) {
        const int mc = min(SMAX, m - s0);

        __syncthreads();   // previous pass done with smem
        // stage xs[j][0..1023] for mc samples: 2048 float4 slots, 8/thread
        #pragma unroll
        for (int k = 0; k < 8; ++k) {
            const int fq = tid + k * THREADS;   // 0..2047
            const int j  = fq >> 8;
            const int dq = fq & 255;
            smem4[fq] = (j < mc) ? x4[(size_t)mem[s0 + j] * (D_DIM / 4) + dq]
                                 : (f4)(0.f);
        }
        __syncthreads();

        f4 acc[SMAX];
        #pragma unroll
        for (int j = 0; j < SMAX; ++j) acc[j] = (f4)(0.f);

        // 64 rows per thread, 4 rows per iteration; nt loads (zero reuse)
        #pragma unroll 4
        for (int k = 0; k < 16; ++k) {
            const f4 t0 = __builtin_nontemporal_load(&Tp[(size_t)(4 * k + 0) * (D_DIM / 4)]);
            const f4 t1 = __builtin_nontemporal_load(&Tp[(size_t)(4 * k + 1) * (D_DIM / 4)]);
            const f4 t2 = __builtin_nontemporal_load(&Tp[(size_t)(4 * k + 2) * (D_DIM / 4)]);
            const f4 t3 = __builtin_nontemporal_load(&Tp[(size_t)(4 * k + 3) * (D_DIM / 4)]);
            const int dq = sl * 16 + k;   // float4 index of rows 4k..4k+3 in xs
            #pragma unroll
            for (int j = 0; j < SMAX; ++j) {
                const f4 xv = smem4[j * (D_DIM / 4) + dq];  // broadcast read
                acc[j].x = fmaf(xv.x, t0.x, fmaf(xv.y, t1.x, fmaf(xv.z, t2.x, fmaf(xv.w, t3.x, acc[j].x))));
                acc[j].y = fmaf(xv.x, t0.y, fmaf(xv.y, t1.y, fmaf(xv.z, t2.y, fmaf(xv.w, t3.y, acc[j].y))));
                acc[j].z = fmaf(xv.x, t0.z, fmaf(xv.y, t1.z, fmaf(xv.z, t2.z, fmaf(xv.w, t3.z, acc[j].z))));
                acc[j].w = fmaf(xv.x, t0.w, fmaf(xv.y, t1.w, fmaf(xv.z, t2.w, fmaf(xv.w, t3.w, acc[j].w))));
            }
        }

        __syncthreads();   // all xs reads complete; smem becomes red[]
        #pragma unroll
        for (int j = 0; j < SMAX; ++j)
            smem4[(j * DSL + sl) * (ECOLS / 4) + eth] = acc[j];
        __syncthreads();

        // fold 16 d-slices: 512 outputs (8 samples x 64 cols), 2 per thread
        #pragma unroll
        for (int o2 = 0; o2 < 2; ++o2) {
            const int o = tid + o2 * THREADS;   // 0..511
            const int j = o >> 6;
            const int c = o & 63;
            if (j < mc) {
                float s = 0.f;
                #pragma unroll
                for (int ss = 0; ss < DSL; ++ss)
                    s += smem[(j * DSL + ss) * ECOLS + c];
                __builtin_nontemporal_store(
                    s, &out[(size_t)mem[s0 + j] * D_DIM + e0 + c]);
            }
        }
    }
}

extern "C" void kernel_launch(void* const* d_in, const int* in_sizes, int n_in,
                              void* d_out, int out_size, void* d_ws, size_t ws_size,
                              hipStream_t stream)
{
    const float* x = (const float*)d_in[0];
    const int*   g = (const int*)d_in[1];
    const float* T = (const float*)d_in[2];
    float* out = (float*)d_out;

    dim3 grid(G_DIM, ECH);   // 40 x 16 = 640 blocks
    leqfc_fused<<<grid, THREADS, 0, stream>>>(x, g, T, out);
}